// Round 1
// baseline (44.753 us; speedup 1.0000x reference)
//
#include <hip/hip_runtime.h>

// logp for LogisticModel: out[r] = sum_t [ -0.5*((x_t - 0.9*x_{t-1} - sigmoid(s_t))/0.1)^2
//                                          - log(0.1) - 0.5*log(2*pi) ]
// with x_{-1} = 0. Pure elementwise over shifted x + per-row reduction.
// Memory-bound: 268 MB read @ ~6.3 TB/s achievable -> ~43 us floor.

#define DECAY 0.9f

__global__ __launch_bounds__(256) void logp_kernel(
    const float* __restrict__ s, const float* __restrict__ x,
    float* __restrict__ out, int T) {
  const int row  = blockIdx.x;
  const int tid  = threadIdx.x;
  const int lane = tid & 63;

  const float* sr = s + (size_t)row * (size_t)T;
  const float* xr = x + (size_t)row * (size_t)T;

  float acc = 0.f;

  // 256 threads x float4 = 1024 elements per sweep; T=8192 -> 8 sweeps.
  for (int j = tid * 4; j < T; j += 1024) {
    const float4 s4 = *reinterpret_cast<const float4*>(sr + j);
    const float4 x4 = *reinterpret_cast<const float4*>(xr + j);

    // previous element for this thread's first lane: neighbor thread's x4.w
    float prev = __shfl_up(x4.w, 1);
    if (lane == 0) prev = (j == 0) ? 0.f : xr[j - 1];  // L1/L2 hit

    const float b0 = 1.f / (1.f + __expf(-s4.x));
    const float b1 = 1.f / (1.f + __expf(-s4.y));
    const float b2 = 1.f / (1.f + __expf(-s4.z));
    const float b3 = 1.f / (1.f + __expf(-s4.w));

    const float r0 = x4.x - DECAY * prev - b0;
    const float r1 = x4.y - DECAY * x4.x - b1;
    const float r2 = x4.z - DECAY * x4.y - b2;
    const float r3 = x4.w - DECAY * x4.z - b3;

    acc += r0 * r0 + r1 * r1;
    acc += r2 * r2 + r3 * r3;
  }

  // wave64 reduction
  #pragma unroll
  for (int off = 32; off >= 1; off >>= 1)
    acc += __shfl_down(acc, off);

  __shared__ float wave_sums[4];
  if (lane == 0) wave_sums[tid >> 6] = acc;
  __syncthreads();

  if (tid == 0) {
    const float tot = wave_sums[0] + wave_sums[1] + wave_sums[2] + wave_sums[3];
    // C = -log(0.1) - 0.5*log(2*pi)
    const float C = 1.3836465597893728f;
    // 0.5 / NOISE^2 = 50
    out[row] = (float)T * C - 50.0f * tot;
  }
}

extern "C" void kernel_launch(void* const* d_in, const int* in_sizes, int n_in,
                              void* d_out, int out_size, void* d_ws, size_t ws_size,
                              hipStream_t stream) {
  const float* s = (const float*)d_in[0];
  const float* x = (const float*)d_in[1];
  float* out = (float*)d_out;

  const int B = out_size;                 // 4096
  const int T = in_sizes[0] / B;          // 8192

  logp_kernel<<<B, 256, 0, stream>>>(s, x, out, T);
}